// Round 2
// baseline (239.632 us; speedup 1.0000x reference)
//
#include <hip/hip_runtime.h>
#include <hip/hip_bf16.h>
#include <stdint.h>

typedef float f32x4 __attribute__((ext_vector_type(4)));
typedef _Float16 half8 __attribute__((ext_vector_type(8)));
typedef _Float16 half2_ __attribute__((ext_vector_type(2)));

#define B_ 4096
#define T_ 256
#define D_ 18
#define H_ 32
#define GK 8192   // T_*H_
#define GN 512
#define KSPLIT 4
#define SLOT 520  // hist ring slot stride in halves (16*32 + 8 pad)

#define K1_ 1.442695041f
#define K2_ 2.885390082f
#define X2_ __builtin_amdgcn_exp2f
#define RCP_ __builtin_amdgcn_rcpf

// Barrier draining ONLY LDS (lgkmcnt) — global loads/stores stay in flight.
__device__ __forceinline__ void ldsbar() {
  asm volatile("s_waitcnt lgkmcnt(0)\n\ts_barrier" ::: "memory");
}

// ---------- kernel 1: W1 fp32 -> fp16 (RNE) ----------
__global__ __launch_bounds__(256) void cvtw1_kernel(const float* __restrict__ w1,
                                                    unsigned short* __restrict__ dst) {
  int i = blockIdx.x * 256 + threadIdx.x;  // float4 index, total 1048576
  float4 v = ((const float4*)w1)[i];
  unsigned short a = __builtin_bit_cast(unsigned short, (_Float16)v.x);
  unsigned short b = __builtin_bit_cast(unsigned short, (_Float16)v.y);
  unsigned short c = __builtin_bit_cast(unsigned short, (_Float16)v.z);
  unsigned short d = __builtin_bit_cast(unsigned short, (_Float16)v.w);
  uint2 o; o.x = (unsigned)a | ((unsigned)b << 16); o.y = (unsigned)c | ((unsigned)d << 16);
  ((uint2*)dst)[i] = o;
}

// ---------- kernel 2: MFMA LSTM ----------
// R8: 4 waves (256 thr) per 16-elem group, 256 blocks -> 1 wave/SIMD.
// Wave w computes 2 m-tiles covering gates (i,f) / (g,o) for h-rows
// lq*8 + w*2 + {0,1}: lane (lq,lr) produces exactly the 2 h values inside
// its OWN next-step B-fragment k-range [lq*8, lq*8+8), so ring layout and
// the b128 fragment read are unchanged; write is one packed half2.
// Per step/wave: 2 wh-MFMA + 2 precomputed wx-MFMA + 2 act chains
// (7 trans each: ei,ef,eg,eo,ec + 2 rcp — f's rcp folded into c's).
__global__ __launch_bounds__(256) void lstm_kernel(
    const float* __restrict__ batch, const float* __restrict__ W_ih,
    const float* __restrict__ W_hh, const float* __restrict__ b_ih,
    const float* __restrict__ b_hh, _Float16* __restrict__ hs) {
  __shared__ _Float16 hist[16 * SLOT];
  __shared__ _Float16 xs[2 * 4096];  // [buf][t(8)][elem(16) x k(32)]

  const int tid = (int)threadIdx.x;
  const int lane = tid & 63;
  const int w = tid >> 6;        // 0..3
  const int lq = lane >> 4;
  const int lr = lane & 15;
  const int b0 = (int)blockIdx.x * 16;

  // A fragments (lane holds A[m=lr][k=lq*8+j]).
  // Tile mt, row m: gate = mt*2 + ((m&3)>>1), hrow = (m>>2)*8 + w*2 + (m&1).
  half8 wx0, wx1, wh0, wh1;
  {
    int gq = (lr & 3) >> 1;
    int hrow = (lr >> 2) * 8 + w * 2 + (lr & 1);
    int g0 = (0 + gq) * 32 + hrow;   // tile0: i / f
    int g1 = (2 + gq) * 32 + hrow;   // tile1: g / o
#pragma unroll
    for (int j = 0; j < 8; ++j) {
      int k = lq * 8 + j;
      wx0[j] = (k < D_) ? (_Float16)W_ih[g0 * D_ + k] : (_Float16)0.0f;
      wx1[j] = (k < D_) ? (_Float16)W_ih[g1 * D_ + k] : (_Float16)0.0f;
      wh0[j] = (_Float16)W_hh[g0 * H_ + k];
      wh1[j] = (_Float16)W_hh[g1 * H_ + k];
    }
  }
  // bias for C rows m=lq*4+r: tile0 gates (r>>1), tile1 gates 2+(r>>1)
  f32x4 bias0, bias1;
#pragma unroll
  for (int r = 0; r < 4; ++r) {
    int hrow = lq * 8 + w * 2 + (r & 1);
    int ga = (r >> 1) * 32 + hrow;
    int gb = (2 + (r >> 1)) * 32 + hrow;
    bias0[r] = b_ih[ga] + b_hh[ga];
    bias1[r] = b_ih[gb] + b_hh[gb];
  }

  // fragment-read offset (row = elem, 32-half rows, chunk-swizzled)
  const int swz = (lr >> 1) & 3;
  const int rdo = lr * 32 + ((lq ^ swz) << 3);
  // half2 write base: logical k = lq*8 + w*2 (+s) -> chunk lq^swz, pos w*2
  const int wro2 = rdo + w * 2;

  // flush mapping (ring -> hs, coalesced 16B/lane, 2 units per thread)
  int fl_rd[2]; _Float16* fl_wp[2];
#pragma unroll
  for (int u = 0; u < 2; ++u) {
    int idx = tid + u * 256;
    int fe = idx >> 5, fs = (idx >> 2) & 7, fg = idx & 3;
    fl_rd[u] = fs * SLOT + fe * 32 + ((fg ^ ((fe >> 1) & 3)) << 3);
    fl_wp[u] = hs + (size_t)(b0 + fe) * GK + fs * H_ + fg * 8;
  }

  // x slab staging: 576 float4 per 8t over 256 threads (2 + tail 1)
  const int e0 = tid / 36, q0 = tid - e0 * 36;
  const int i1 = tid + 256, e1 = i1 / 36, q1 = i1 - e1 * 36;
  const int i2 = tid + 512, e2 = i2 / 36, q2 = i2 - e2 * 36;  // tid<64 only
  const float* xld0 = batch + (size_t)(b0 + e0) * (T_ * D_) + q0 * 4;
  const float* xld1 = batch + (size_t)(b0 + e1) * (T_ * D_) + q1 * 4;
  const float* xld2 = batch + (size_t)(b0 + e2) * (T_ * D_) + q2 * 4;
  float4 xv0, xv1, xv2;

#define XLOAD(tb)                                                              \
  do {                                                                         \
    xv0 = *(const float4*)(xld0 + (tb) * 144);                                 \
    xv1 = *(const float4*)(xld1 + (tb) * 144);                                 \
    if (tid < 64) xv2 = *(const float4*)(xld2 + (tb) * 144);                   \
  } while (0)

#define XPUT(E, Q, V, buf)                                                     \
  do {                                                                         \
    int swz_ = ((E) >> 1) & 3;                                                 \
    _Pragma("unroll") for (int j = 0; j < 4; ++j) {                            \
      int f_ = (Q) * 4 + j;                                                    \
      int to_ = (f_ * 57) >> 10; /* f/18 for f<1024 */                         \
      int d_ = f_ - to_ * 18;                                                  \
      float val_ = (j == 0) ? (V).x : (j == 1) ? (V).y : (j == 2) ? (V).z : (V).w; \
      xs[(buf) * 4096 + to_ * 512 + (E) * 32 + (((d_ >> 3) ^ swz_) << 3) + (d_ & 7)] = \
          (_Float16)val_;                                                      \
    }                                                                          \
  } while (0)

#define XSTORE(buf)                                                            \
  do {                                                                         \
    XPUT(e0, q0, xv0, buf);                                                    \
    XPUT(e1, q1, xv1, buf);                                                    \
    if (tid < 64) XPUT(e2, q2, xv2, buf);                                      \
  } while (0)

// step tt (0..7): h(t-1) from ring; AX0/AX1 hold bias + Wih*x(t); trailing
// args = next step's ax precompute (issues under the hf lgkm wait).
#define STEP(tt, AX0, AX1, ...)                                                \
  do {                                                                         \
    const _Float16* hrd = ((tt) == 0 ? po + 7 * SLOT : pr + ((tt)-1) * SLOT);  \
    half8 hf = *(const half8*)&hrd[rdo];                                       \
    f32x4 a0 = __builtin_amdgcn_mfma_f32_16x16x32_f16(wh0, hf, AX0, 0, 0, 0);  \
    f32x4 a1 = __builtin_amdgcn_mfma_f32_16x16x32_f16(wh1, hf, AX1, 0, 0, 0);  \
    __VA_ARGS__;                                                               \
    _Float16 hp0, hp1;                                                         \
    {                                                                          \
      float ei = X2_(-K1_ * a0[0]); float ef = X2_(-K1_ * a0[2]);              \
      float eg = X2_(-K2_ * a1[0]); float eo = X2_(-K1_ * a1[2]);              \
      float pi_ = (1.0f + ei) * (1.0f + eg);                                   \
      float num = fmaf(c0, pi_, (1.0f + ef) * (1.0f - eg));                    \
      c0 = num * RCP_((1.0f + ef) * pi_);                                      \
      float ec = X2_(-K2_ * c0);                                               \
      hp0 = (_Float16)((1.0f - ec) * RCP_((1.0f + eo) * (1.0f + ec)));         \
    }                                                                          \
    {                                                                          \
      float ei = X2_(-K1_ * a0[1]); float ef = X2_(-K1_ * a0[3]);              \
      float eg = X2_(-K2_ * a1[1]); float eo = X2_(-K1_ * a1[3]);              \
      float pi_ = (1.0f + ei) * (1.0f + eg);                                   \
      float num = fmaf(c1, pi_, (1.0f + ef) * (1.0f - eg));                    \
      c1 = num * RCP_((1.0f + ef) * pi_);                                      \
      float ec = X2_(-K2_ * c1);                                               \
      hp1 = (_Float16)((1.0f - ec) * RCP_((1.0f + eo) * (1.0f + ec)));         \
    }                                                                          \
    half2_ hp; hp[0] = hp0; hp[1] = hp1;                                       \
    *(half2_*)&pr[(tt)*SLOT + wro2] = hp;                                      \
    ldsbar();                                                                  \
  } while (0)

  XLOAD(0);  // loads fly while we zero LDS
  for (int i = tid; i < 16 * SLOT; i += 256) hist[i] = (_Float16)0.0f;
  for (int i = tid; i < 8192; i += 256) xs[i] = (_Float16)0.0f;
  ldsbar();
  XSTORE(0);   // one-time vmcnt wait
  XLOAD(1);
  ldsbar();

  float c0 = 0.0f, c1 = 0.0f;
  for (int blk = 0; blk < 32; ++blk) {
    const int p = blk & 1;
    _Float16* pr = hist + p * (8 * SLOT);
    const _Float16* po = hist + (p ^ 1) * (8 * SLOT);
    const int xo = p * 4096;

    // whole window's x fragments -> registers (shared by both wx tiles)
    half8 xq[8];
#pragma unroll
    for (int j = 0; j < 8; ++j) xq[j] = *(const half8*)&xs[xo + j * 512 + rdo];
    f32x4 axA0 = __builtin_amdgcn_mfma_f32_16x16x32_f16(wx0, xq[0], bias0, 0, 0, 0);
    f32x4 axA1 = __builtin_amdgcn_mfma_f32_16x16x32_f16(wx1, xq[0], bias1, 0, 0, 0);
    f32x4 axB0, axB1;

    STEP(0, axA0, axA1,
         axB0 = __builtin_amdgcn_mfma_f32_16x16x32_f16(wx0, xq[1], bias0, 0, 0, 0);
         axB1 = __builtin_amdgcn_mfma_f32_16x16x32_f16(wx1, xq[1], bias1, 0, 0, 0));
    STEP(1, axB0, axB1,
         axA0 = __builtin_amdgcn_mfma_f32_16x16x32_f16(wx0, xq[2], bias0, 0, 0, 0);
         axA1 = __builtin_amdgcn_mfma_f32_16x16x32_f16(wx1, xq[2], bias1, 0, 0, 0));
    STEP(2, axA0, axA1,
         axB0 = __builtin_amdgcn_mfma_f32_16x16x32_f16(wx0, xq[3], bias0, 0, 0, 0);
         axB1 = __builtin_amdgcn_mfma_f32_16x16x32_f16(wx1, xq[3], bias1, 0, 0, 0));
    STEP(3, axB0, axB1,
         axA0 = __builtin_amdgcn_mfma_f32_16x16x32_f16(wx0, xq[4], bias0, 0, 0, 0);
         axA1 = __builtin_amdgcn_mfma_f32_16x16x32_f16(wx1, xq[4], bias1, 0, 0, 0));
    // stage next slab mid-window (vmcnt: loads issued a full window ago)
    if (blk < 31) XSTORE(p ^ 1);
    if (blk < 30) XLOAD(blk + 2);
    STEP(4, axA0, axA1,
         axB0 = __builtin_amdgcn_mfma_f32_16x16x32_f16(wx0, xq[5], bias0, 0, 0, 0);
         axB1 = __builtin_amdgcn_mfma_f32_16x16x32_f16(wx1, xq[5], bias1, 0, 0, 0));
    // flush PREVIOUS window's ring half -> global (other parity, no barrier)
    if (blk) {
#pragma unroll
      for (int u = 0; u < 2; ++u) {
        half8 hv = *(const half8*)&hist[(p ^ 1) * (8 * SLOT) + fl_rd[u]];
        *(half8*)(fl_wp[u] + (size_t)(blk - 1) * (8 * H_)) = hv;
      }
    }
    STEP(5, axB0, axB1,
         axA0 = __builtin_amdgcn_mfma_f32_16x16x32_f16(wx0, xq[6], bias0, 0, 0, 0);
         axA1 = __builtin_amdgcn_mfma_f32_16x16x32_f16(wx1, xq[6], bias1, 0, 0, 0));
    STEP(6, axA0, axA1,
         axB0 = __builtin_amdgcn_mfma_f32_16x16x32_f16(wx0, xq[7], bias0, 0, 0, 0);
         axB1 = __builtin_amdgcn_mfma_f32_16x16x32_f16(wx1, xq[7], bias1, 0, 0, 0));
    STEP(7, axB0, axB1, );
  }
  // final flush (window 31, parity 1)
#pragma unroll
  for (int u = 0; u < 2; ++u) {
    half8 hv = *(const half8*)&hist[8 * SLOT + fl_rd[u]];
    *(half8*)(fl_wp[u] + (size_t)31 * (8 * H_)) = hv;
  }
#undef STEP
#undef XSTORE
#undef XPUT
#undef XLOAD
}

// ---------- kernel 3: fp16 MFMA GEMM, BM=BN=128 BK=64, split-K=4 ----------
// Double-buffered LDS, 2-deep register prefetch with COMPILE-TIME set/buffer
// parity (named sets va0/va1 — R6's va[p] dynamic index spilled to scratch).
__global__ __launch_bounds__(256, 2) void gemm_kernel(
    const _Float16* __restrict__ Ahs, const _Float16* __restrict__ Bw1,
    float* __restrict__ part) {
  __shared__ _Float16 As[2 * 128 * 64];
  __shared__ _Float16 Bs[2 * 128 * 64];

  const int bid = (int)blockIdx.x;
  const int m0 = (bid & 31) << 7;
  const int n0 = ((bid >> 5) & 3) << 7;
  const int ksp = bid >> 7;
  const int k0 = ksp << 11;   // * 2048
  float* outp = part + (size_t)ksp * ((size_t)B_ * GN);

  const int tid = (int)threadIdx.x;
  const int lane = tid & 63, w = tid >> 6;
  const int wm = w & 1, wn = w >> 1;
  const int lq = lane >> 4, lr = lane & 15;

  const _Float16* gA[4]; const _Float16* gB[4]; int lp[4];
#pragma unroll
  for (int j = 0; j < 4; ++j) {
    int p = tid + 256 * j;               // 0..1023
    int row = p >> 3, q = p & 7, cg = q ^ (row & 7);
    gA[j] = Ahs + (size_t)(m0 + row) * GK + k0 + cg * 8;
    gB[j] = Bw1 + (size_t)(n0 + row) * GK + k0 + cg * 8;
    lp[j] = p * 8;
  }

  int offA[4][2], offB[4][2];
#pragma unroll
  for (int mt = 0; mt < 4; ++mt)
#pragma unroll
    for (int ks = 0; ks < 2; ++ks) {
      int m = wm * 64 + mt * 16 + lr;
      offA[mt][ks] = m * 64 + (((lq + ks * 4) ^ (m & 7)) << 3);
      int n = wn * 64 + mt * 16 + lr;
      offB[mt][ks] = n * 64 + (((lq + ks * 4) ^ (n & 7)) << 3);
    }

  f32x4 acc[4][4];
#pragma unroll
  for (int mt = 0; mt < 4; ++mt)
#pragma unroll
    for (int nt = 0; nt < 4; ++nt) {
      acc[mt][nt][0] = 0.f; acc[mt][nt][1] = 0.f;
      acc[mt][nt][2] = 0.f; acc[mt][nt][3] = 0.f;
    }

  // preload k-chunks 0 (set0) and 1 (set1)
  half8 va0[4], vb0[4], va1[4], vb1[4];
#pragma unroll
  for (int j = 0; j < 4; ++j) {
    va0[j] = *(const half8*)gA[j];        vb0[j] = *(const half8*)gB[j];
    va1[j] = *(const half8*)(gA[j] + 64); vb1[j] = *(const half8*)(gB[j] + 64);
    gA[j] += 128; gB[j] += 128;
  }

#define GPHASE(SET, POFF, guard)                                               \
  do {                                                                         \
    _Pragma("unroll") for (int j = 0; j < 4; ++j) {                            \
      *(half8*)&As[(POFF) + lp[j]] = va##SET[j];                               \
      *(half8*)&Bs[(POFF) + lp[j]] = vb##SET[j];                               \
    }                                                                          \
    if (guard) {                                                               \
      _Pragma("unroll") for (int j = 0; j < 4; ++j) {                          \
        va##SET[j] = *(const half8*)gA[j];                                     \
        vb##SET[j] = *(const half8*)gB[j];                                     \
        gA[j] += 64; gB[j] += 64;                                              \
      }                                                                        \
    }                                                                          \
    ldsbar();                                                                  \
    half8 af[4][2], bf[4][2];                                                  \
    _Pragma("unroll") for (int mt = 0; mt < 4; ++mt)                           \
      _Pragma("unroll") for (int ks = 0; ks < 2; ++ks) {                       \
        af[mt][ks] = *(const half8*)&As[(POFF) + offA[mt][ks]];                \
        bf[mt][ks] = *(const half8*)&Bs[(POFF) + offB[mt][ks]];                \
      }                                                                        \
    _Pragma("unroll") for (int ks = 0; ks < 2; ++ks)                           \
      _Pragma("unroll") for (int mt = 0; mt < 4; ++mt)                         \
        _Pragma("unroll") for (int nt = 0; nt < 4; ++nt)                       \
          acc[mt][nt] = __builtin_amdgcn_mfma_f32_16x16x32_f16(                \
              af[mt][ks], bf[nt][ks], acc[mt][nt], 0, 0, 0);                   \
  } while (0)

  for (int it2 = 0; it2 < 16; ++it2) {
    const bool g = (it2 < 15);
    GPHASE(0, 0, g);
    GPHASE(1, 8192, g);
  }
#undef GPHASE

  // epilogue: C layout col=lr, row=lq*4+reg; plain stores to this split's buffer
#pragma unroll
  for (int mt = 0; mt < 4; ++mt)
#pragma unroll
    for (int nt = 0; nt < 4; ++nt) {
      int n = n0 + wn * 64 + nt * 16 + lr;
#pragma unroll
      for (int r = 0; r < 4; ++r) {
        int m = m0 + wm * 64 + mt * 16 + lq * 4 + r;
        outp[(size_t)m * GN + n] = acc[mt][nt][r];
      }
    }
}

// ---------- kernel 4: head — sum KSPLIT partials, bias, relu, dot W2 ----------
__global__ __launch_bounds__(256) void head_kernel(const float* __restrict__ part,
                                                   const float* __restrict__ b1,
                                                   const float* __restrict__ W2,
                                                   const float* __restrict__ b2,
                                                   float* __restrict__ out) {
  const int b = (int)(blockIdx.x * 4 + (threadIdx.x >> 6));
  const int l = (int)(threadIdx.x & 63);
  const size_t stride = (size_t)B_ * GN;
  const float4* b14 = (const float4*)b1;
  const float4* w4 = (const float4*)W2;
  float s = 0.0f;
#pragma unroll
  for (int p = 0; p < 2; ++p) {
    int i = p * 64 + l;
    float4 hv = ((const float4*)(part + (size_t)b * GN))[i];
#pragma unroll
    for (int sp = 1; sp < KSPLIT; ++sp) {
      float4 pv = ((const float4*)(part + sp * stride + (size_t)b * GN))[i];
      hv.x += pv.x; hv.y += pv.y; hv.z += pv.z; hv.w += pv.w;
    }
    float4 bv = b14[i], wv = w4[i];
    float t0 = fmaxf(hv.x + bv.x, 0.0f);
    float t1 = fmaxf(hv.y + bv.y, 0.0f);
    float t2 = fmaxf(hv.z + bv.z, 0.0f);
    float t3 = fmaxf(hv.w + bv.w, 0.0f);
    s = fmaf(t0, wv.x, s); s = fmaf(t1, wv.y, s);
    s = fmaf(t2, wv.z, s); s = fmaf(t3, wv.w, s);
  }
#pragma unroll
  for (int off = 32; off >= 1; off >>= 1) s += __shfl_xor(s, off);
  if (l == 0) out[b] = s + b2[0];
}

extern "C" void kernel_launch(void* const* d_in, const int* in_sizes, int n_in,
                              void* d_out, int out_size, void* d_ws, size_t ws_size,
                              hipStream_t stream) {
  const float* batch = (const float*)d_in[0];
  const float* W_ih = (const float*)d_in[1];
  const float* W_hh = (const float*)d_in[2];
  const float* b_ih = (const float*)d_in[3];
  const float* b_hh = (const float*)d_in[4];
  const float* W1 = (const float*)d_in[5];
  const float* b1 = (const float*)d_in[6];
  const float* W2 = (const float*)d_in[7];
  const float* b2 = (const float*)d_in[8];
  float* out = (float*)d_out;

  char* ws = (char*)d_ws;
  _Float16* hs = (_Float16*)ws;                         // 4096*8192*2 = 67108864 B
  _Float16* w1h = (_Float16*)(ws + 67108864);           // 512*8192*2  =  8388608 B
  float* part = (float*)(ws + 67108864 + 8388608);      // 4*4096*512*4 = 33554432 B

  cvtw1_kernel<<<4096, 256, 0, stream>>>(W1, (unsigned short*)w1h);
  lstm_kernel<<<256, 256, 0, stream>>>(batch, W_ih, W_hh, b_ih, b_hh, hs);
  gemm_kernel<<<512, 256, 0, stream>>>(hs, w1h, part);
  head_kernel<<<1024, 256, 0, stream>>>(part, b1, W2, b2, out);
}

// Round 3
// 227.991 us; speedup vs baseline: 1.0511x; 1.0511x over previous
//
#include <hip/hip_runtime.h>
#include <hip/hip_bf16.h>
#include <stdint.h>

typedef float f32x4 __attribute__((ext_vector_type(4)));
typedef _Float16 half8 __attribute__((ext_vector_type(8)));

#define B_ 4096
#define T_ 256
#define D_ 18
#define H_ 32
#define GK 8192   // T_*H_
#define GN 512
#define KSPLIT 4
#define SLOT 520  // hist ring slot stride in halves (16*32 + 8 pad)

#define K1_ 1.442695041f
#define K2_ 2.885390082f
#define X2_ __builtin_amdgcn_exp2f
#define RCP_ __builtin_amdgcn_rcpf

// Barrier draining ONLY LDS (lgkmcnt) — global loads/stores stay in flight.
__device__ __forceinline__ void ldsbar() {
  asm volatile("s_waitcnt lgkmcnt(0)\n\ts_barrier" ::: "memory");
}
// Full barrier: drain vmcnt (global_load_lds) + lgkmcnt, then barrier.
__device__ __forceinline__ void fullbar() {
  asm volatile("s_waitcnt vmcnt(0) lgkmcnt(0)\n\ts_barrier" ::: "memory");
}
// async global -> LDS, 16B per lane. LDS dest must be wave-uniform base
// (HW adds lane*16); global src is per-lane (carries the swizzle).
__device__ __forceinline__ void gl_lds16(const _Float16* g, _Float16* l) {
  __builtin_amdgcn_global_load_lds(
      (const __attribute__((address_space(1))) unsigned int*)g,
      (__attribute__((address_space(3))) unsigned int*)l, 16, 0, 0);
}

// ---------- kernel 1: W1 fp32 -> fp16 (RNE) ----------
__global__ __launch_bounds__(256) void cvtw1_kernel(const float* __restrict__ w1,
                                                    unsigned short* __restrict__ dst) {
  int i = blockIdx.x * 256 + threadIdx.x;  // float4 index, total 1048576
  float4 v = ((const float4*)w1)[i];
  unsigned short a = __builtin_bit_cast(unsigned short, (_Float16)v.x);
  unsigned short b = __builtin_bit_cast(unsigned short, (_Float16)v.y);
  unsigned short c = __builtin_bit_cast(unsigned short, (_Float16)v.z);
  unsigned short d = __builtin_bit_cast(unsigned short, (_Float16)v.w);
  uint2 o; o.x = (unsigned)a | ((unsigned)b << 16); o.y = (unsigned)c | ((unsigned)d << 16);
  ((uint2*)dst)[i] = o;
}

// ---------- kernel 2: MFMA LSTM (R1 8-wave structure + 7-trans merge) ----------
// Block = 512 thr (8 waves) owns 16 batch elems. Wave w: tile-rows m =
// hl*4+gate, h_row = w*4+hl, orig W row = gate*32 + w*4 + hl. C layout
// row=lq*4+reg, col=lr: lane (lq,lr) gets (i,f,g,o) of h_row=w*4+lq, elem lr.
//  * all 8 x-fragments of a window preloaded to regs (xq[8])
//  * acc_x(t+1) = mfma(wx,xq[t+1],bias) one step AHEAD (ax0/ax1)
//  * hist ring = 16 slots (2 windows): flush of window k runs inside k+1
//  * 7 trans/h: ei,ef,eg,eo,ec + 2 rcp (f's rcp folded into c's — R2-verified)
__global__ __launch_bounds__(512) void lstm_kernel(
    const float* __restrict__ batch, const float* __restrict__ W_ih,
    const float* __restrict__ W_hh, const float* __restrict__ b_ih,
    const float* __restrict__ b_hh, _Float16* __restrict__ hs) {
  __shared__ _Float16 hist[16 * SLOT];
  __shared__ _Float16 xs[2 * 4096];  // [buf][t(8)][elem(16) x k(32)]

  const int tid = (int)threadIdx.x;
  const int lane = tid & 63;
  const int w = tid >> 6;
  const int lq = lane >> 4;
  const int lr = lane & 15;
  const int b0 = (int)blockIdx.x * 16;

  // constant A-fragments
  half8 wx, wh;
  {
    int grow = (lr & 3) * 32 + w * 4 + (lr >> 2);
#pragma unroll
    for (int j = 0; j < 8; ++j) {
      int k = lq * 8 + j;
      wx[j] = (k < D_) ? (_Float16)W_ih[grow * D_ + k] : (_Float16)0.0f;
      wh[j] = (_Float16)W_hh[grow * H_ + k];
    }
  }
  f32x4 bias4;
#pragma unroll
  for (int r = 0; r < 4; ++r) {
    int g = r * 32 + w * 4 + lq;
    bias4[r] = b_ih[g] + b_hh[g];
  }

  // fragment-read offset (row = elem, 32-half rows, chunk-swizzled)
  const int rdo = lr * 32 + ((lq ^ ((lr >> 1) & 3)) << 3);
  const int kcol = w * 4 + lq;
  const int wro = lr * 32 + ((((kcol >> 3) ^ ((lr >> 1) & 3))) << 3) + (kcol & 7);

  // flush mapping (ring -> hs, coalesced 16B/lane)
  const int fe = tid >> 5;
  const int fs = (tid >> 2) & 7;
  const int fg = tid & 3;
  const int fl_rd = fs * SLOT + fe * 32 + ((fg ^ ((fe >> 1) & 3)) << 3);
  _Float16* fl_wp = hs + (size_t)(b0 + fe) * GK + fs * H_ + fg * 8;

  // x slab staging: 576 float4 per 8t; thread -> (elem e, q-th float4 of 36)
  const int e0 = tid / 36, q0 = tid - e0 * 36;
  const int i1 = tid + 512;
  const int e1 = i1 / 36, q1 = i1 - e1 * 36;  // only tid<64
  const float* xld0 = batch + (size_t)(b0 + e0) * (T_ * D_) + q0 * 4;
  const float* xld1 = batch + (size_t)(b0 + e1) * (T_ * D_) + q1 * 4;
  float4 xv0, xv1;

#define XLOAD(tb)                                                              \
  do {                                                                         \
    xv0 = *(const float4*)(xld0 + (tb) * 144);                                 \
    if (tid < 64) xv1 = *(const float4*)(xld1 + (tb) * 144);                   \
  } while (0)

#define XPUT(E, Q, V, buf)                                                     \
  do {                                                                         \
    int swz_ = ((E) >> 1) & 3;                                                 \
    _Pragma("unroll") for (int j = 0; j < 4; ++j) {                            \
      int f_ = (Q) * 4 + j;                                                    \
      int to_ = (f_ * 57) >> 10; /* f/18 for f<1024 */                         \
      int d_ = f_ - to_ * 18;                                                  \
      float val_ = (j == 0) ? (V).x : (j == 1) ? (V).y : (j == 2) ? (V).z : (V).w; \
      xs[(buf) * 4096 + to_ * 512 + (E) * 32 + (((d_ >> 3) ^ swz_) << 3) + (d_ & 7)] = \
          (_Float16)val_;                                                      \
    }                                                                          \
  } while (0)

#define XSTORE(buf)                                                            \
  do {                                                                         \
    XPUT(e0, q0, xv0, buf);                                                    \
    if (tid < 64) XPUT(e1, q1, xv1, buf);                                      \
  } while (0)

// step tt (0..7): h(t-1) from ring; AXC holds bias + Wih*x(t); PRE computes
// next step's ax under the hf lgkm wait. Merged activations (7 trans):
//   c' = [c*(1+ei)(1+eg) + (1+ef)(1-eg)] / [(1+ef)(1+ei)(1+eg)]
//   h  = (1-ec) / [(1+eo)(1+ec)]
#define STEP(tt, AXC, PRE)                                                     \
  do {                                                                         \
    _Float16* hrd = ((tt) == 0 ? po + 7 * SLOT : pr + ((tt)-1) * SLOT);        \
    half8 hf = *(const half8*)&hrd[rdo];                                       \
    f32x4 acc = __builtin_amdgcn_mfma_f32_16x16x32_f16(wh, hf, AXC, 0, 0, 0);  \
    PRE;                                                                       \
    float ei = X2_(-K1_ * acc[0]);                                             \
    float ef = X2_(-K1_ * acc[1]);                                             \
    float eg = X2_(-K2_ * acc[2]);                                             \
    float eo = X2_(-K1_ * acc[3]);                                             \
    float pi_ = (1.0f + ei) * (1.0f + eg);                                     \
    float num = fmaf(c, pi_, (1.0f + ef) * (1.0f - eg));                       \
    c = num * RCP_((1.0f + ef) * pi_);                                         \
    float ec = X2_(-K2_ * c);                                                  \
    float h = (1.0f - ec) * RCP_((1.0f + eo) * (1.0f + ec));                   \
    pr[(tt)*SLOT + wro] = (_Float16)h;                                         \
    ldsbar();                                                                  \
  } while (0)

  XLOAD(0);  // loads fly while we zero LDS
  for (int i = tid; i < 16 * SLOT; i += 512) hist[i] = (_Float16)0.0f;
  for (int i = tid; i < 8192; i += 512) xs[i] = (_Float16)0.0f;
  ldsbar();
  XSTORE(0);   // one-time vmcnt wait
  XLOAD(1);
  ldsbar();

  float c = 0.0f;
  for (int blk = 0; blk < 32; ++blk) {
    const int p = blk & 1;
    _Float16* pr = hist + p * (8 * SLOT);
    _Float16* po = hist + (p ^ 1) * (8 * SLOT);
    const int xo = p * 4096;

    // preload the whole window's x fragments into registers
    half8 xq[8];
#pragma unroll
    for (int j = 0; j < 8; ++j) xq[j] = *(const half8*)&xs[xo + j * 512 + rdo];
    f32x4 ax0, ax1;
    ax0 = __builtin_amdgcn_mfma_f32_16x16x32_f16(wx, xq[0], bias4, 0, 0, 0);

    STEP(0, ax0, ax1 = __builtin_amdgcn_mfma_f32_16x16x32_f16(wx, xq[1], bias4, 0, 0, 0));
    STEP(1, ax1, ax0 = __builtin_amdgcn_mfma_f32_16x16x32_f16(wx, xq[2], bias4, 0, 0, 0));
    STEP(2, ax0, ax1 = __builtin_amdgcn_mfma_f32_16x16x32_f16(wx, xq[3], bias4, 0, 0, 0));
    STEP(3, ax1, ax0 = __builtin_amdgcn_mfma_f32_16x16x32_f16(wx, xq[4], bias4, 0, 0, 0));
    // stage next slab mid-window (vmcnt: loads issued a full window ago)
    if (blk < 31) XSTORE(p ^ 1);
    if (blk < 30) XLOAD(blk + 2);
    STEP(4, ax0, ax1 = __builtin_amdgcn_mfma_f32_16x16x32_f16(wx, xq[5], bias4, 0, 0, 0));
    // flush PREVIOUS window's ring half -> global (other parity, no barrier)
    if (blk) {
      half8 hv = *(const half8*)&hist[(p ^ 1) * (8 * SLOT) + fl_rd];
      *(half8*)(fl_wp + (size_t)(blk - 1) * (8 * H_)) = hv;
    }
    STEP(5, ax1, ax0 = __builtin_amdgcn_mfma_f32_16x16x32_f16(wx, xq[6], bias4, 0, 0, 0));
    STEP(6, ax0, ax1 = __builtin_amdgcn_mfma_f32_16x16x32_f16(wx, xq[7], bias4, 0, 0, 0));
    STEP(7, ax1, );
  }
  // final flush (window 31, parity 1)
  {
    half8 hv = *(const half8*)&hist[8 * SLOT + fl_rd];
    *(half8*)(fl_wp + (size_t)31 * (8 * H_)) = hv;
  }
#undef STEP
#undef XSTORE
#undef XPUT
#undef XLOAD
}

// ---------- kernel 3: fp16 MFMA GEMM, BM=BN=128 BK=64, split-K=4 ----------
// R9: global_load_lds direct staging (m97 structure). LDS layout is linear
// in tid (lane*16B) with the XOR-swizzle folded into the GLOBAL source
// address — exactly the pre-swizzled-src + linear-dest pattern the HW wants.
// Per phase: issue 8 global_load_lds_dwordx4 into buf^1, ds_read frags from
// buf, 32 MFMA, then vmcnt(0)+lgkm(0)+barrier.
__global__ __launch_bounds__(256, 2) void gemm_kernel(
    const _Float16* __restrict__ Ahs, const _Float16* __restrict__ Bw1,
    float* __restrict__ part) {
  __shared__ _Float16 As[2 * 128 * 64];
  __shared__ _Float16 Bs[2 * 128 * 64];

  const int bid = (int)blockIdx.x;
  const int m0 = (bid & 31) << 7;
  const int n0 = ((bid >> 5) & 3) << 7;
  const int ksp = bid >> 7;
  const int k0 = ksp << 11;   // * 2048
  float* outp = part + (size_t)ksp * ((size_t)B_ * GN);

  const int tid = (int)threadIdx.x;
  const int lane = tid & 63, w = tid >> 6;
  const int wm = w & 1, wn = w >> 1;
  const int lq = lane >> 4, lr = lane & 15;

  // global sources (per-lane, swizzled) + LDS dests (wave-uniform base)
  const _Float16* gA[4]; const _Float16* gB[4];
  _Float16* lA[4]; _Float16* lB[4];
#pragma unroll
  for (int j = 0; j < 4; ++j) {
    int p = tid + 256 * j;               // 0..1023
    int row = p >> 3, q = p & 7, cg = q ^ (row & 7);
    gA[j] = Ahs + (size_t)(m0 + row) * GK + k0 + cg * 8;
    gB[j] = Bw1 + (size_t)(n0 + row) * GK + k0 + cg * 8;
    int wbase = (w * 64 + 256 * j) * 8;  // halves; HW adds lane*16B
    lA[j] = As + wbase;
    lB[j] = Bs + wbase;
  }

  int offA[4][2], offB[4][2];
#pragma unroll
  for (int mt = 0; mt < 4; ++mt)
#pragma unroll
    for (int ks = 0; ks < 2; ++ks) {
      int m = wm * 64 + mt * 16 + lr;
      offA[mt][ks] = m * 64 + (((lq + ks * 4) ^ (m & 7)) << 3);
      int n = wn * 64 + mt * 16 + lr;
      offB[mt][ks] = n * 64 + (((lq + ks * 4) ^ (n & 7)) << 3);
    }

  f32x4 acc[4][4];
#pragma unroll
  for (int mt = 0; mt < 4; ++mt)
#pragma unroll
    for (int nt = 0; nt < 4; ++nt) {
      acc[mt][nt][0] = 0.f; acc[mt][nt][1] = 0.f;
      acc[mt][nt][2] = 0.f; acc[mt][nt][3] = 0.f;
    }

#define STAGE(POFF)                                                            \
  do {                                                                         \
    _Pragma("unroll") for (int j = 0; j < 4; ++j) {                            \
      gl_lds16(gA[j], lA[j] + (POFF));                                         \
      gl_lds16(gB[j], lB[j] + (POFF));                                         \
      gA[j] += 64; gB[j] += 64;                                                \
    }                                                                          \
  } while (0)

  STAGE(0);
  fullbar();

  for (int it = 0; it < 32; ++it) {
    const int POFF = (it & 1) * 8192;
    if (it < 31) STAGE(POFF ^ 8192);   // loads fly over dsread+MFMA
    half8 af[4][2], bf[4][2];
#pragma unroll
    for (int mt = 0; mt < 4; ++mt)
#pragma unroll
      for (int ks = 0; ks < 2; ++ks) {
        af[mt][ks] = *(const half8*)&As[POFF + offA[mt][ks]];
        bf[mt][ks] = *(const half8*)&Bs[POFF + offB[mt][ks]];
      }
#pragma unroll
    for (int ks = 0; ks < 2; ++ks)
#pragma unroll
      for (int mt = 0; mt < 4; ++mt)
#pragma unroll
        for (int nt = 0; nt < 4; ++nt)
          acc[mt][nt] = __builtin_amdgcn_mfma_f32_16x16x32_f16(
              af[mt][ks], bf[nt][ks], acc[mt][nt], 0, 0, 0);
    fullbar();
  }
#undef STAGE

  // epilogue: C layout col=lr, row=lq*4+reg; plain stores to this split's buffer
#pragma unroll
  for (int mt = 0; mt < 4; ++mt)
#pragma unroll
    for (int nt = 0; nt < 4; ++nt) {
      int n = n0 + wn * 64 + nt * 16 + lr;
#pragma unroll
      for (int r = 0; r < 4; ++r) {
        int m = m0 + wm * 64 + mt * 16 + lq * 4 + r;
        outp[(size_t)m * GN + n] = acc[mt][nt][r];
      }
    }
}

// ---------- kernel 4: head — sum KSPLIT partials, bias, relu, dot W2 ----------
__global__ __launch_bounds__(256) void head_kernel(const float* __restrict__ part,
                                                   const float* __restrict__ b1,
                                                   const float* __restrict__ W2,
                                                   const float* __restrict__ b2,
                                                   float* __restrict__ out) {
  const int b = (int)(blockIdx.x * 4 + (threadIdx.x >> 6));
  const int l = (int)(threadIdx.x & 63);
  const size_t stride = (size_t)B_ * GN;
  const float4* b14 = (const float4*)b1;
  const float4* w4 = (const float4*)W2;
  float s = 0.0f;
#pragma unroll
  for (int p = 0; p < 2; ++p) {
    int i = p * 64 + l;
    float4 hv = ((const float4*)(part + (size_t)b * GN))[i];
#pragma unroll
    for (int sp = 1; sp < KSPLIT; ++sp) {
      float4 pv = ((const float4*)(part + sp * stride + (size_t)b * GN))[i];
      hv.x += pv.x; hv.y += pv.y; hv.z += pv.z; hv.w += pv.w;
    }
    float4 bv = b14[i], wv = w4[i];
    float t0 = fmaxf(hv.x + bv.x, 0.0f);
    float t1 = fmaxf(hv.y + bv.y, 0.0f);
    float t2 = fmaxf(hv.z + bv.z, 0.0f);
    float t3 = fmaxf(hv.w + bv.w, 0.0f);
    s = fmaf(t0, wv.x, s); s = fmaf(t1, wv.y, s);
    s = fmaf(t2, wv.z, s); s = fmaf(t3, wv.w, s);
  }
#pragma unroll
  for (int off = 32; off >= 1; off >>= 1) s += __shfl_xor(s, off);
  if (l == 0) out[b] = s + b2[0];
}

extern "C" void kernel_launch(void* const* d_in, const int* in_sizes, int n_in,
                              void* d_out, int out_size, void* d_ws, size_t ws_size,
                              hipStream_t stream) {
  const float* batch = (const float*)d_in[0];
  const float* W_ih = (const float*)d_in[1];
  const float* W_hh = (const float*)d_in[2];
  const float* b_ih = (const float*)d_in[3];
  const float* b_hh = (const float*)d_in[4];
  const float* W1 = (const float*)d_in[5];
  const float* b1 = (const float*)d_in[6];
  const float* W2 = (const float*)d_in[7];
  const float* b2 = (const float*)d_in[8];
  float* out = (float*)d_out;

  char* ws = (char*)d_ws;
  _Float16* hs = (_Float16*)ws;                         // 4096*8192*2 = 67108864 B
  _Float16* w1h = (_Float16*)(ws + 67108864);           // 512*8192*2  =  8388608 B
  float* part = (float*)(ws + 67108864 + 8388608);      // 4*4096*512*4 = 33554432 B

  cvtw1_kernel<<<4096, 256, 0, stream>>>(W1, (unsigned short*)w1h);
  lstm_kernel<<<256, 512, 0, stream>>>(batch, W_ih, W_hh, b_ih, b_hh, hs);
  gemm_kernel<<<512, 256, 0, stream>>>(hs, w1h, part);
  head_kernel<<<1024, 256, 0, stream>>>(part, b1, W2, b2, out);
}

// Round 4
// 224.550 us; speedup vs baseline: 1.0672x; 1.0153x over previous
//
#include <hip/hip_runtime.h>
#include <hip/hip_bf16.h>
#include <stdint.h>

typedef float f32x4 __attribute__((ext_vector_type(4)));
typedef _Float16 half8 __attribute__((ext_vector_type(8)));

#define B_ 4096
#define T_ 256
#define D_ 18
#define H_ 32
#define GK 8192   // T_*H_
#define GN 512
#define KSPLIT 4
#define SLOT 520  // hist ring slot stride in halves (16*32 + 8 pad)

#define K1_ 1.442695041f
#define K2_ 2.885390082f
#define X2_ __builtin_amdgcn_exp2f
#define RCP_ __builtin_amdgcn_rcpf

// Barrier draining ONLY LDS (lgkmcnt) — global loads/stores stay in flight.
__device__ __forceinline__ void ldsbar() {
  asm volatile("s_waitcnt lgkmcnt(0)\n\ts_barrier" ::: "memory");
}
// async global -> LDS, 16B per lane. LDS dest must be wave-uniform base
// (HW adds lane*16); global src is per-lane (carries the swizzle).
__device__ __forceinline__ void gl_lds16(const _Float16* g, _Float16* l) {
  __builtin_amdgcn_global_load_lds(
      (const __attribute__((address_space(1))) unsigned int*)g,
      (__attribute__((address_space(3))) unsigned int*)l, 16, 0, 0);
}

// ---------- kernel 1: W1 fp32 -> fp16 (RNE) ----------
__global__ __launch_bounds__(256) void cvtw1_kernel(const float* __restrict__ w1,
                                                    unsigned short* __restrict__ dst) {
  int i = blockIdx.x * 256 + threadIdx.x;  // float4 index, total 1048576
  float4 v = ((const float4*)w1)[i];
  unsigned short a = __builtin_bit_cast(unsigned short, (_Float16)v.x);
  unsigned short b = __builtin_bit_cast(unsigned short, (_Float16)v.y);
  unsigned short c = __builtin_bit_cast(unsigned short, (_Float16)v.z);
  unsigned short d = __builtin_bit_cast(unsigned short, (_Float16)v.w);
  uint2 o; o.x = (unsigned)a | ((unsigned)b << 16); o.y = (unsigned)c | ((unsigned)d << 16);
  ((uint2*)dst)[i] = o;
}

// ---------- kernel 2: MFMA LSTM (R1 8-wave structure + 7-trans merge) ----------
// Block = 512 thr (8 waves) owns 16 batch elems. Wave w: tile-rows m =
// hl*4+gate, h_row = w*4+hl, orig W row = gate*32 + w*4 + hl. C layout
// row=lq*4+reg, col=lr: lane (lq,lr) gets (i,f,g,o) of h_row=w*4+lq, elem lr.
//  * all 8 x-fragments of a window preloaded to regs (xq[8])
//  * acc_x(t+1) = mfma(wx,xq[t+1],bias) one step AHEAD (ax0/ax1)
//  * hist ring = 16 slots (2 windows): flush of window k runs inside k+1
//  * 7 trans/h: ei,ef,eg,eo,ec + 2 rcp (f's rcp folded into c's)
__global__ __launch_bounds__(512) void lstm_kernel(
    const float* __restrict__ batch, const float* __restrict__ W_ih,
    const float* __restrict__ W_hh, const float* __restrict__ b_ih,
    const float* __restrict__ b_hh, _Float16* __restrict__ hs) {
  __shared__ _Float16 hist[16 * SLOT];
  __shared__ _Float16 xs[2 * 4096];  // [buf][t(8)][elem(16) x k(32)]

  const int tid = (int)threadIdx.x;
  const int lane = tid & 63;
  const int w = tid >> 6;
  const int lq = lane >> 4;
  const int lr = lane & 15;
  const int b0 = (int)blockIdx.x * 16;

  // constant A-fragments
  half8 wx, wh;
  {
    int grow = (lr & 3) * 32 + w * 4 + (lr >> 2);
#pragma unroll
    for (int j = 0; j < 8; ++j) {
      int k = lq * 8 + j;
      wx[j] = (k < D_) ? (_Float16)W_ih[grow * D_ + k] : (_Float16)0.0f;
      wh[j] = (_Float16)W_hh[grow * H_ + k];
    }
  }
  f32x4 bias4;
#pragma unroll
  for (int r = 0; r < 4; ++r) {
    int g = r * 32 + w * 4 + lq;
    bias4[r] = b_ih[g] + b_hh[g];
  }

  // fragment-read offset (row = elem, 32-half rows, chunk-swizzled)
  const int rdo = lr * 32 + ((lq ^ ((lr >> 1) & 3)) << 3);
  const int kcol = w * 4 + lq;
  const int wro = lr * 32 + ((((kcol >> 3) ^ ((lr >> 1) & 3))) << 3) + (kcol & 7);

  // flush mapping (ring -> hs, coalesced 16B/lane)
  const int fe = tid >> 5;
  const int fs = (tid >> 2) & 7;
  const int fg = tid & 3;
  const int fl_rd = fs * SLOT + fe * 32 + ((fg ^ ((fe >> 1) & 3)) << 3);
  _Float16* fl_wp = hs + (size_t)(b0 + fe) * GK + fs * H_ + fg * 8;

  // x slab staging: 576 float4 per 8t; thread -> (elem e, q-th float4 of 36)
  const int e0 = tid / 36, q0 = tid - e0 * 36;
  const int i1 = tid + 512;
  const int e1 = i1 / 36, q1 = i1 - e1 * 36;  // only tid<64
  const float* xld0 = batch + (size_t)(b0 + e0) * (T_ * D_) + q0 * 4;
  const float* xld1 = batch + (size_t)(b0 + e1) * (T_ * D_) + q1 * 4;
  float4 xv0, xv1;

#define XLOAD(tb)                                                              \
  do {                                                                         \
    xv0 = *(const float4*)(xld0 + (tb) * 144);                                 \
    if (tid < 64) xv1 = *(const float4*)(xld1 + (tb) * 144);                   \
  } while (0)

#define XPUT(E, Q, V, buf)                                                     \
  do {                                                                         \
    int swz_ = ((E) >> 1) & 3;                                                 \
    _Pragma("unroll") for (int j = 0; j < 4; ++j) {                            \
      int f_ = (Q) * 4 + j;                                                    \
      int to_ = (f_ * 57) >> 10; /* f/18 for f<1024 */                         \
      int d_ = f_ - to_ * 18;                                                  \
      float val_ = (j == 0) ? (V).x : (j == 1) ? (V).y : (j == 2) ? (V).z : (V).w; \
      xs[(buf) * 4096 + to_ * 512 + (E) * 32 + (((d_ >> 3) ^ swz_) << 3) + (d_ & 7)] = \
          (_Float16)val_;                                                      \
    }                                                                          \
  } while (0)

#define XSTORE(buf)                                                            \
  do {                                                                         \
    XPUT(e0, q0, xv0, buf);                                                    \
    if (tid < 64) XPUT(e1, q1, xv1, buf);                                      \
  } while (0)

// step tt (0..7): h(t-1) from ring; AXC holds bias + Wih*x(t); PRE computes
// next step's ax under the hf lgkm wait. Merged activations (7 trans):
//   c' = [c*(1+ei)(1+eg) + (1+ef)(1-eg)] / [(1+ef)(1+ei)(1+eg)]
//   h  = (1-ec) / [(1+eo)(1+ec)]
#define STEP(tt, AXC, PRE)                                                     \
  do {                                                                         \
    _Float16* hrd = ((tt) == 0 ? po + 7 * SLOT : pr + ((tt)-1) * SLOT);        \
    half8 hf = *(const half8*)&hrd[rdo];                                       \
    f32x4 acc = __builtin_amdgcn_mfma_f32_16x16x32_f16(wh, hf, AXC, 0, 0, 0);  \
    PRE;                                                                       \
    float ei = X2_(-K1_ * acc[0]);                                             \
    float ef = X2_(-K1_ * acc[1]);                                             \
    float eg = X2_(-K2_ * acc[2]);                                             \
    float eo = X2_(-K1_ * acc[3]);                                             \
    float pi_ = (1.0f + ei) * (1.0f + eg);                                     \
    float num = fmaf(c, pi_, (1.0f + ef) * (1.0f - eg));                       \
    c = num * RCP_((1.0f + ef) * pi_);                                         \
    float ec = X2_(-K2_ * c);                                                  \
    float h = (1.0f - ec) * RCP_((1.0f + eo) * (1.0f + ec));                   \
    pr[(tt)*SLOT + wro] = (_Float16)h;                                         \
    ldsbar();                                                                  \
  } while (0)

  XLOAD(0);  // loads fly while we zero LDS
  for (int i = tid; i < 16 * SLOT; i += 512) hist[i] = (_Float16)0.0f;
  for (int i = tid; i < 8192; i += 512) xs[i] = (_Float16)0.0f;
  ldsbar();
  XSTORE(0);   // one-time vmcnt wait
  XLOAD(1);
  ldsbar();

  float c = 0.0f;
  for (int blk = 0; blk < 32; ++blk) {
    const int p = blk & 1;
    _Float16* pr = hist + p * (8 * SLOT);
    _Float16* po = hist + (p ^ 1) * (8 * SLOT);
    const int xo = p * 4096;

    // preload the whole window's x fragments into registers
    half8 xq[8];
#pragma unroll
    for (int j = 0; j < 8; ++j) xq[j] = *(const half8*)&xs[xo + j * 512 + rdo];
    f32x4 ax0, ax1;
    ax0 = __builtin_amdgcn_mfma_f32_16x16x32_f16(wx, xq[0], bias4, 0, 0, 0);

    STEP(0, ax0, ax1 = __builtin_amdgcn_mfma_f32_16x16x32_f16(wx, xq[1], bias4, 0, 0, 0));
    STEP(1, ax1, ax0 = __builtin_amdgcn_mfma_f32_16x16x32_f16(wx, xq[2], bias4, 0, 0, 0));
    STEP(2, ax0, ax1 = __builtin_amdgcn_mfma_f32_16x16x32_f16(wx, xq[3], bias4, 0, 0, 0));
    STEP(3, ax1, ax0 = __builtin_amdgcn_mfma_f32_16x16x32_f16(wx, xq[4], bias4, 0, 0, 0));
    // stage next slab mid-window (vmcnt: loads issued a full window ago)
    if (blk < 31) XSTORE(p ^ 1);
    if (blk < 30) XLOAD(blk + 2);
    STEP(4, ax0, ax1 = __builtin_amdgcn_mfma_f32_16x16x32_f16(wx, xq[5], bias4, 0, 0, 0));
    // flush PREVIOUS window's ring half -> global (other parity, no barrier)
    if (blk) {
      half8 hv = *(const half8*)&hist[(p ^ 1) * (8 * SLOT) + fl_rd];
      *(half8*)(fl_wp + (size_t)(blk - 1) * (8 * H_)) = hv;
    }
    STEP(5, ax1, ax0 = __builtin_amdgcn_mfma_f32_16x16x32_f16(wx, xq[6], bias4, 0, 0, 0));
    STEP(6, ax0, ax1 = __builtin_amdgcn_mfma_f32_16x16x32_f16(wx, xq[7], bias4, 0, 0, 0));
    STEP(7, ax1, );
  }
  // final flush (window 31, parity 1)
  {
    half8 hv = *(const half8*)&hist[8 * SLOT + fl_rd];
    *(half8*)(fl_wp + (size_t)31 * (8 * H_)) = hv;
  }
#undef STEP
#undef XSTORE
#undef XPUT
#undef XLOAD
}

// ---------- kernel 3: fp16 MFMA GEMM, BM=BN=128 BK=64, split-K=4 ----------
// R10: counted-vmcnt pipeline (T4). Prologue stages BOTH buffers (16 loads
// in flight). Per iteration: vmcnt(8)+bar (current buf landed, next buf
// still flying) -> ds_read frags -> lgkm(0)+bar (all waves done reading)
// -> restage this buf for it+2 -> MFMA. No vmcnt(0) drain in the main loop:
// each load gets ~2 iterations of latency cover. Last iteration peeled.
__global__ __launch_bounds__(256, 2) void gemm_kernel(
    const _Float16* __restrict__ Ahs, const _Float16* __restrict__ Bw1,
    float* __restrict__ part) {
  __shared__ _Float16 As[2 * 128 * 64];
  __shared__ _Float16 Bs[2 * 128 * 64];

  const int bid = (int)blockIdx.x;
  const int m0 = (bid & 31) << 7;
  const int n0 = ((bid >> 5) & 3) << 7;
  const int ksp = bid >> 7;
  const int k0 = ksp << 11;   // * 2048
  float* outp = part + (size_t)ksp * ((size_t)B_ * GN);

  const int tid = (int)threadIdx.x;
  const int lane = tid & 63, w = tid >> 6;
  const int wm = w & 1, wn = w >> 1;
  const int lq = lane >> 4, lr = lane & 15;

  // global sources (per-lane, swizzled) + LDS dests (wave-uniform base)
  const _Float16* gA[4]; const _Float16* gB[4];
  _Float16* lA[4]; _Float16* lB[4];
#pragma unroll
  for (int j = 0; j < 4; ++j) {
    int p = tid + 256 * j;               // 0..1023
    int row = p >> 3, q = p & 7, cg = q ^ (row & 7);
    gA[j] = Ahs + (size_t)(m0 + row) * GK + k0 + cg * 8;
    gB[j] = Bw1 + (size_t)(n0 + row) * GK + k0 + cg * 8;
    int wbase = (w * 64 + 256 * j) * 8;  // halves; HW adds lane*16B
    lA[j] = As + wbase;
    lB[j] = Bs + wbase;
  }

  int offA[4][2], offB[4][2];
#pragma unroll
  for (int mt = 0; mt < 4; ++mt)
#pragma unroll
    for (int ks = 0; ks < 2; ++ks) {
      int m = wm * 64 + mt * 16 + lr;
      offA[mt][ks] = m * 64 + (((lq + ks * 4) ^ (m & 7)) << 3);
      int n = wn * 64 + mt * 16 + lr;
      offB[mt][ks] = n * 64 + (((lq + ks * 4) ^ (n & 7)) << 3);
    }

  f32x4 acc[4][4];
#pragma unroll
  for (int mt = 0; mt < 4; ++mt)
#pragma unroll
    for (int nt = 0; nt < 4; ++nt) {
      acc[mt][nt][0] = 0.f; acc[mt][nt][1] = 0.f;
      acc[mt][nt][2] = 0.f; acc[mt][nt][3] = 0.f;
    }

#define STAGE(POFF)                                                            \
  do {                                                                         \
    _Pragma("unroll") for (int j = 0; j < 4; ++j) {                            \
      gl_lds16(gA[j], lA[j] + (POFF));                                         \
      gl_lds16(gB[j], lB[j] + (POFF));                                         \
      gA[j] += 64; gB[j] += 64;                                                \
    }                                                                          \
  } while (0)

#define FRAGS(POFF)                                                            \
  half8 af[4][2], bf[4][2];                                                    \
  _Pragma("unroll") for (int mt = 0; mt < 4; ++mt)                             \
    _Pragma("unroll") for (int ks = 0; ks < 2; ++ks) {                         \
      af[mt][ks] = *(const half8*)&As[(POFF) + offA[mt][ks]];                  \
      bf[mt][ks] = *(const half8*)&Bs[(POFF) + offB[mt][ks]];                  \
    }

#define MFMAS                                                                  \
  _Pragma("unroll") for (int ks = 0; ks < 2; ++ks)                             \
    _Pragma("unroll") for (int mt = 0; mt < 4; ++mt)                           \
      _Pragma("unroll") for (int nt = 0; nt < 4; ++nt)                         \
        acc[mt][nt] = __builtin_amdgcn_mfma_f32_16x16x32_f16(                  \
            af[mt][ks], bf[nt][ks], acc[mt][nt], 0, 0, 0);

  STAGE(0);      // buf0 <- k-chunk 0
  STAGE(8192);   // buf1 <- k-chunk 1   (16 loads in flight)

  for (int it = 0; it < 31; ++it) {
    const int POFF = (it & 1) * 8192;
    // current buffer's 8 loads (oldest) landed; next buffer's 8 keep flying
    asm volatile("s_waitcnt vmcnt(8)\n\ts_barrier" ::: "memory");
    FRAGS(POFF);
    // all waves finished reading this buffer -> safe to overwrite
    asm volatile("s_waitcnt lgkmcnt(0)\n\ts_barrier" ::: "memory");
    if (it < 30) STAGE(POFF);   // refill for it+2, flies over the MFMAs
    MFMAS;
  }
  {  // it = 31 (peeled: only 8 loads outstanding -> full drain)
    asm volatile("s_waitcnt vmcnt(0)\n\ts_barrier" ::: "memory");
    FRAGS(8192);
    MFMAS;
  }
#undef MFMAS
#undef FRAGS
#undef STAGE

  // epilogue: C layout col=lr, row=lq*4+reg; plain stores to this split's buffer
#pragma unroll
  for (int mt = 0; mt < 4; ++mt)
#pragma unroll
    for (int nt = 0; nt < 4; ++nt) {
      int n = n0 + wn * 64 + nt * 16 + lr;
#pragma unroll
      for (int r = 0; r < 4; ++r) {
        int m = m0 + wm * 64 + mt * 16 + lq * 4 + r;
        outp[(size_t)m * GN + n] = acc[mt][nt][r];
      }
    }
}

// ---------- kernel 4: head — sum KSPLIT partials, bias, relu, dot W2 ----------
__global__ __launch_bounds__(256) void head_kernel(const float* __restrict__ part,
                                                   const float* __restrict__ b1,
                                                   const float* __restrict__ W2,
                                                   const float* __restrict__ b2,
                                                   float* __restrict__ out) {
  const int b = (int)(blockIdx.x * 4 + (threadIdx.x >> 6));
  const int l = (int)(threadIdx.x & 63);
  const size_t stride = (size_t)B_ * GN;
  const float4* b14 = (const float4*)b1;
  const float4* w4 = (const float4*)W2;
  float s = 0.0f;
#pragma unroll
  for (int p = 0; p < 2; ++p) {
    int i = p * 64 + l;
    float4 hv = ((const float4*)(part + (size_t)b * GN))[i];
#pragma unroll
    for (int sp = 1; sp < KSPLIT; ++sp) {
      float4 pv = ((const float4*)(part + sp * stride + (size_t)b * GN))[i];
      hv.x += pv.x; hv.y += pv.y; hv.z += pv.z; hv.w += pv.w;
    }
    float4 bv = b14[i], wv = w4[i];
    float t0 = fmaxf(hv.x + bv.x, 0.0f);
    float t1 = fmaxf(hv.y + bv.y, 0.0f);
    float t2 = fmaxf(hv.z + bv.z, 0.0f);
    float t3 = fmaxf(hv.w + bv.w, 0.0f);
    s = fmaf(t0, wv.x, s); s = fmaf(t1, wv.y, s);
    s = fmaf(t2, wv.z, s); s = fmaf(t3, wv.w, s);
  }
#pragma unroll
  for (int off = 32; off >= 1; off >>= 1) s += __shfl_xor(s, off);
  if (l == 0) out[b] = s + b2[0];
}

extern "C" void kernel_launch(void* const* d_in, const int* in_sizes, int n_in,
                              void* d_out, int out_size, void* d_ws, size_t ws_size,
                              hipStream_t stream) {
  const float* batch = (const float*)d_in[0];
  const float* W_ih = (const float*)d_in[1];
  const float* W_hh = (const float*)d_in[2];
  const float* b_ih = (const float*)d_in[3];
  const float* b_hh = (const float*)d_in[4];
  const float* W1 = (const float*)d_in[5];
  const float* b1 = (const float*)d_in[6];
  const float* W2 = (const float*)d_in[7];
  const float* b2 = (const float*)d_in[8];
  float* out = (float*)d_out;

  char* ws = (char*)d_ws;
  _Float16* hs = (_Float16*)ws;                         // 4096*8192*2 = 67108864 B
  _Float16* w1h = (_Float16*)(ws + 67108864);           // 512*8192*2  =  8388608 B
  float* part = (float*)(ws + 67108864 + 8388608);      // 4*4096*512*4 = 33554432 B

  cvtw1_kernel<<<4096, 256, 0, stream>>>(W1, (unsigned short*)w1h);
  lstm_kernel<<<256, 512, 0, stream>>>(batch, W_ih, W_hh, b_ih, b_hh, hs);
  gemm_kernel<<<512, 256, 0, stream>>>(hs, w1h, part);
  head_kernel<<<1024, 256, 0, stream>>>(part, b1, W2, b2, out);
}